// Round 1
// 94.789 us; speedup vs baseline: 1.0059x; 1.0059x over previous
//
#include <hip/hip_runtime.h>

// PITLoss: dists[b,i,j] = mean_t (x[b,j,t] - y[b,i,t])^2 ; out = sum_b min over
// 24 permutations of sum_i dists[b,i,perm[i]].
// Memory-bound: 67.1 MB read once -> ~11 us floor at 6.3 TB/s.
//
// R2 theory: top-5 rocprof dispatches are all 256-MiB workspace-poison fills
// (~42 us @ 6.4 TB/s); pit_partial is <41.6 us (absent from top-5) but still
// well above the ~11 us floor. Hypothesis: read-latency bound at 2 blocks/CU
// (8 waves/CU, 25% occupancy) with per-iteration vmcnt drains.
// R2 change: CHUNKS 64->128 (1024 blocks = 4 blocks/CU), ITERS 4->2 with ALL
// 16 float4 loads issued before first use (full prefetch, ~96 VGPR), and
// __launch_bounds__(256,4) to guarantee 16 waves/CU. Predicted: pit_partial
// ~15 us, dur_us 95 -> ~65-72. If dur_us unchanged, the poison fill dominates
// the timed region and the kernel is at its floor.

#define B_ 8
#define C_ 4
#define T_ 262144
#define CHUNKS 128     // blocks per batch
#define THREADS 256
#define ITERS 2        // float4 iterations per thread: (T_/4)/(CHUNKS*THREADS)

__global__ __launch_bounds__(THREADS, 4) void pit_partial(
    const float* __restrict__ x, const float* __restrict__ y,
    float* __restrict__ partial)
{
    const int chunk = blockIdx.x;
    const int b = blockIdx.y;
    const int tid = threadIdx.x;

    const float4* __restrict__ xb = (const float4*)(x + (size_t)b * C_ * T_);
    const float4* __restrict__ yb = (const float4*)(y + (size_t)b * C_ * T_);
    const int T4 = T_ / 4;
    const int base = chunk * (THREADS * ITERS) + tid;

    // Issue ALL loads up front: 16 independent float4 loads (16 KB/wave in
    // flight) before any vmcnt wait. Static indexing -> stays in VGPRs.
    float4 xv[ITERS][C_], yv[ITERS][C_];
#pragma unroll
    for (int it = 0; it < ITERS; ++it) {
        const int idx = base + it * THREADS;
#pragma unroll
        for (int c = 0; c < C_; ++c) {
            xv[it][c] = xb[(size_t)c * T4 + idx];
            yv[it][c] = yb[(size_t)c * T4 + idx];
        }
    }

    float acc[16];
#pragma unroll
    for (int p = 0; p < 16; ++p) acc[p] = 0.f;

#pragma unroll
    for (int it = 0; it < ITERS; ++it) {
#pragma unroll
        for (int i = 0; i < C_; ++i) {
#pragma unroll
            for (int j = 0; j < C_; ++j) {
                const float4 a = xv[it][j];
                const float4 d = yv[it][i];
                const float e0 = a.x - d.x;
                const float e1 = a.y - d.y;
                const float e2 = a.z - d.z;
                const float e3 = a.w - d.w;
                acc[i * 4 + j] += e0 * e0 + e1 * e1 + e2 * e2 + e3 * e3;
            }
        }
    }

    // wave-64 butterfly reduce each of the 16 sums (once per thread).
    // ~96 ds_swizzle + 96 adds; overlapped with other waves' loads (not the
    // bottleneck at 4 blocks/CU: ~6k cyc/CU vs ~26k cyc/CU memory).
#pragma unroll
    for (int p = 0; p < 16; ++p) {
        float v = acc[p];
#pragma unroll
        for (int off = 32; off >= 1; off >>= 1)
            v += __shfl_xor(v, off, 64);
        acc[p] = v;
    }

    __shared__ float red[4][16];
    const int lane = tid & 63;
    const int wave = tid >> 6;
    if (lane == 0) {
#pragma unroll
        for (int p = 0; p < 16; ++p) red[wave][p] = acc[p];
    }
    __syncthreads();
    if (tid < 16) {
        const float s = red[0][tid] + red[1][tid] + red[2][tid] + red[3][tid];
        // layout: partial[ij][b][chunk] -> contiguous over chunk for kernel 2
        partial[((size_t)tid * B_ + b) * CHUNKS + chunk] = s;
    }
}

__global__ __launch_bounds__(128) void pit_final(
    const float* __restrict__ partial, float* __restrict__ out)
{
    __shared__ float dists[B_][16];
    __shared__ float minb[B_];
    const int tid = threadIdx.x;   // 128 threads = 16 ij * 8 b

    {
        const int ij = tid >> 3;
        const int b  = tid & 7;
        const float4* src =
            (const float4*)(partial + ((size_t)ij * B_ + b) * CHUNKS);
        float s = 0.f;
#pragma unroll
        for (int k = 0; k < CHUNKS / 4; ++k) {
            const float4 v = src[k];
            s += v.x + v.y + v.z + v.w;
        }
        dists[b][ij] = s * (1.0f / (float)T_);
    }
    __syncthreads();

    if (tid < B_) {
        static const int P[24][4] = {
            {0,1,2,3},{0,1,3,2},{0,2,1,3},{0,2,3,1},{0,3,1,2},{0,3,2,1},
            {1,0,2,3},{1,0,3,2},{1,2,0,3},{1,2,3,0},{1,3,0,2},{1,3,2,0},
            {2,0,1,3},{2,0,3,1},{2,1,0,3},{2,1,3,0},{2,3,0,1},{2,3,1,0},
            {3,0,1,2},{3,0,2,1},{3,1,0,2},{3,1,2,0},{3,2,0,1},{3,2,1,0}};
        const float* d = dists[tid];
        float best = 3.4e38f;
#pragma unroll
        for (int p = 0; p < 24; ++p) {
            const float c = d[0 + P[p][0]] + d[4 + P[p][1]]
                          + d[8 + P[p][2]] + d[12 + P[p][3]];
            best = fminf(best, c);
        }
        minb[tid] = best;
    }
    __syncthreads();

    if (tid == 0) {
        float s = 0.f;
#pragma unroll
        for (int b = 0; b < B_; ++b) s += minb[b];
        out[0] = s;
    }
}

extern "C" void kernel_launch(void* const* d_in, const int* in_sizes, int n_in,
                              void* d_out, int out_size, void* d_ws, size_t ws_size,
                              hipStream_t stream) {
    const float* x = (const float*)d_in[0];
    const float* y = (const float*)d_in[1];
    float* partial = (float*)d_ws;   // 16 * 8 * 128 floats = 64 KB

    dim3 grid(CHUNKS, B_);
    pit_partial<<<grid, THREADS, 0, stream>>>(x, y, partial);
    pit_final<<<1, 128, 0, stream>>>(partial, (float*)d_out);
}